// Round 8
// baseline (703.328 us; speedup 1.0000x reference)
//
#include <hip/hip_runtime.h>

#define TT 1024
#define DD 32
#define HH 64

typedef __fp16 h2 __attribute__((ext_vector_type(2)));

__device__ __forceinline__ float fsig(float x) {
    float e = __builtin_amdgcn_exp2f(-1.4426950408889634f * x);
    return __builtin_amdgcn_rcpf(1.0f + e);
}

template<int CTRL>
__device__ __forceinline__ float fdpp(float x) {
    int r = __builtin_amdgcn_mov_dpp(__builtin_bit_cast(int, x), CTRL, 0xf, 0xf, true);
    return __builtin_bit_cast(float, r);
}

// lane^4 swizzle (BitMode: xor=4, and=0x1F)
__device__ __forceinline__ float fswz4(float x) {
    int r = __builtin_amdgcn_ds_swizzle(__builtin_bit_cast(int, x), 0x101F);
    return __builtin_bit_cast(float, r);
}

struct __attribute__((aligned(16))) H16 { h2 p[8]; };  // 16 f16 = 32 B

__device__ __forceinline__ h2 pk(float a, float b) {
    return __builtin_amdgcn_cvt_pkrtz(a, b);
}

// ---------------------------------------------------------------------------
// Kernel 1: gx[b][t][j*4+q] = x[b][t] . W_ih_l0[q*64+j] + b_ih + b_hh  (f16)
// grid = 256 b * 16 tq, block = 256 threads (tid = j*4+q)
// ---------------------------------------------------------------------------
__global__ __launch_bounds__(256) void gx_precompute(
    const float* __restrict__ x, const float* __restrict__ w_ih_l0,
    const float* __restrict__ b_ih_l0, const float* __restrict__ b_hh_l0,
    __fp16* __restrict__ gx)
{
    const int blk = blockIdx.x;
    const int b   = blk >> 4;
    const int tq  = blk & 15;          // 64 timesteps per block
    const int tid = threadIdx.x;
    const int q   = tid & 3;
    const int j   = tid >> 2;
    const int g   = q * 64 + j;

    __shared__ __attribute__((aligned(16))) h2 xlds[512];   // 32 t x 32 k (f16)

    h2 wk[16];
    {
        const float4* wp = (const float4*)(w_ih_l0 + g * DD);
        #pragma unroll
        for (int i = 0; i < 8; ++i) {
            float4 f = wp[i];
            wk[2*i]   = pk(f.x, f.y);
            wk[2*i+1] = pk(f.z, f.w);
        }
    }
    const float bias = b_ih_l0[g] + b_hh_l0[g];

    const float* xb = x + (size_t)b * (TT*DD) + tq * 64 * DD;
    __fp16* gxo = gx + ((size_t)b * TT + tq * 64) * 256 + tid;

    #pragma unroll
    for (int sc = 0; sc < 2; ++sc) {
        __syncthreads();
        {
            float4 f = *(const float4*)(xb + sc * 1024 + tid * 4);
            xlds[tid*2]   = pk(f.x, f.y);
            xlds[tid*2+1] = pk(f.z, f.w);
        }
        __syncthreads();
        for (int tl = 0; tl < 32; ++tl) {
            H16 xa = *(const H16*)&xlds[tl*16];
            H16 xb2 = *(const H16*)&xlds[tl*16 + 8];
            float s0 = 0.f, s1 = 0.f;
            #pragma unroll
            for (int k = 0; k < 8; ++k) s0 = __builtin_amdgcn_fdot2(wk[k],   xa.p[k],  s0, false);
            #pragma unroll
            for (int k = 0; k < 8; ++k) s1 = __builtin_amdgcn_fdot2(wk[8+k], xb2.p[k], s1, false);
            gxo[(sc*32 + tl) * 256] = (__fp16)(s0 + s1 + bias);
        }
    }
}

// ---------------------------------------------------------------------------
// Kernel 2: recurrence. 768 threads/block, block = batch element.
//  tid<256  : L1. lid=tid; j=lid>>2, q=lid&3. Lane owns gate (q,j) FULL K=64
//             (h-part; x-part precomputed in gx). 32 weight dwords. No reduce.
//  tid>=256 : L2. lid=tid-256 (0..511); j=lid>>3, m=lid&3, half=(lid>>2)&1.
//             Lane owns gate (m,j) over one K-half (h1 if half=0, h2 if
//             half=1); xor-4 swizzle combines halves. 32 weight dwords.
// ---------------------------------------------------------------------------
__global__ __launch_bounds__(768, 3) void lstm2_pre(
    const float* __restrict__ w_hh_l0,
    const float* __restrict__ w_ih_l1, const float* __restrict__ w_hh_l1,
    const float* __restrict__ b_ih_l1, const float* __restrict__ b_hh_l1,
    const float* __restrict__ w_fc,   const float* __restrict__ b_fc,
    const __fp16* __restrict__ gx,
    float* __restrict__ out)
{
    const int b    = blockIdx.x;
    const int tid  = threadIdx.x;
    const bool isL1 = tid < 256;
    const int lid  = isL1 ? tid : (tid - 256);   // L1: 0..255, L2: 0..511
    const int q    = lid & 3;                    // L1 gate
    const int jL1  = lid >> 2;
    const int m    = lid & 3;                    // L2 gate
    const int half = (lid >> 2) & 1;
    const int jL2  = lid >> 3;                   // 0..63 for L2

    __shared__ __attribute__((aligned(32))) __fp16 h1s[2][HH];
    __shared__ __attribute__((aligned(32))) __fp16 h2sB[2][HH];
    if (tid < HH) {
        h1s[0][tid] = (__fp16)0.f; h1s[1][tid] = (__fp16)0.f;
        h2sB[0][tid] = (__fp16)0.f; h2sB[1][tid] = (__fp16)0.f;
    }

    // activation constants: gate 2 -> tanh(x)=2*sigma(2x)-1, else sigma(x)
    const int gsel = isL1 ? q : m;
    const float kk = (gsel == 2) ? -2.885390081777927f : -1.4426950408889634f;
    const float aa = (gsel == 2) ? 2.0f : 1.0f;
    const float bb = (gsel == 2) ? -1.0f : 0.0f;

    // 32 packed-f16 weight dwords per lane
    h2 wh[32];
    float bias = 0.f;
    if (isL1) {
        const float4* wp = (const float4*)(w_hh_l0 + (q*64 + jL1) * HH);
        #pragma unroll
        for (int i = 0; i < 16; ++i) {
            float4 f = wp[i];
            wh[2*i]   = pk(f.x, f.y);
            wh[2*i+1] = pk(f.z, f.w);
        }
    } else {
        const float* wrow = (half == 0) ? (w_ih_l1 + (m*64 + jL2) * HH)
                                        : (w_hh_l1 + (m*64 + jL2) * HH);
        const float4* wp = (const float4*)wrow;
        #pragma unroll
        for (int i = 0; i < 16; ++i) {
            float4 f = wp[i];
            wh[2*i]   = pk(f.x, f.y);
            wh[2*i+1] = pk(f.z, f.w);
        }
        bias = b_ih_l1[m*64 + jL2] + b_hh_l1[m*64 + jL2];
    }

    float c = 0.0f;

    // gx stream for L1: element ((b*1024 + t)*256 + lid)
    const __fp16* gxp = gx + ((size_t)b << 18) + lid;
    float gxv = isL1 ? (float)gxp[0] : 0.f;

    __syncthreads();

    for (int t = 0; t <= TT; ++t) {
        const int prev = (t + 1) & 1;
        const int cur  = t & 1;
        if (isL1) {
            if (t < TT) {
                const int tn = (t + 1 < TT) ? (t + 1) : t;
                float gnext = (float)gxp[(size_t)tn << 8];

                H16 hA = *(const H16*)&h1s[prev][0];
                H16 hB = *(const H16*)&h1s[prev][16];
                H16 hC = *(const H16*)&h1s[prev][32];
                H16 hD = *(const H16*)&h1s[prev][48];

                float s0 = gxv, s1 = 0.f, s2 = 0.f, s3 = 0.f;
                #pragma unroll
                for (int k = 0; k < 8; ++k) {
                    s0 = __builtin_amdgcn_fdot2(wh[k],      hA.p[k], s0, false);
                    s1 = __builtin_amdgcn_fdot2(wh[8 + k],  hB.p[k], s1, false);
                    s2 = __builtin_amdgcn_fdot2(wh[16 + k], hC.p[k], s2, false);
                    s3 = __builtin_amdgcn_fdot2(wh[24 + k], hD.p[k], s3, false);
                }
                float S = (s0 + s1) + (s2 + s3);

                float e = __builtin_amdgcn_exp2f(kk * S);
                float v = aa * __builtin_amdgcn_rcpf(1.0f + e) + bb;

                float gi = fdpp<0x00>(v);
                float gf = fdpp<0x55>(v);
                float gg = fdpp<0xAA>(v);
                float go = fdpp<0xFF>(v);
                c = gf * c + gi * gg;
                float e2 = __builtin_amdgcn_exp2f(-2.885390081777927f * c);
                float th = 2.0f * __builtin_amdgcn_rcpf(1.0f + e2) - 1.0f;
                float hv = go * th;
                if (q == 0) h1s[cur][jL1] = (__fp16)hv;

                gxv = gnext;
            }
        } else {
            if (t > 0) {
                const __fp16* hsrc = half ? &h2sB[prev][0] : &h1s[prev][0];
                H16 hA = *(const H16*)&hsrc[0];
                H16 hB = *(const H16*)&hsrc[16];
                H16 hC = *(const H16*)&hsrc[32];
                H16 hD = *(const H16*)&hsrc[48];

                float s0 = 0.f, s1 = 0.f, s2 = 0.f, s3 = 0.f;
                #pragma unroll
                for (int k = 0; k < 8; ++k) {
                    s0 = __builtin_amdgcn_fdot2(wh[k],      hA.p[k], s0, false);
                    s1 = __builtin_amdgcn_fdot2(wh[8 + k],  hB.p[k], s1, false);
                    s2 = __builtin_amdgcn_fdot2(wh[16 + k], hC.p[k], s2, false);
                    s3 = __builtin_amdgcn_fdot2(wh[24 + k], hD.p[k], s3, false);
                }
                float Sp = (s0 + s1) + (s2 + s3);
                float S = Sp + fswz4(Sp) + bias;

                float e = __builtin_amdgcn_exp2f(kk * S);
                float v = aa * __builtin_amdgcn_rcpf(1.0f + e) + bb;

                float gi = fdpp<0x00>(v);
                float gf = fdpp<0x55>(v);
                float gg = fdpp<0xAA>(v);
                float go = fdpp<0xFF>(v);
                c = gf * c + gi * gg;
                float e2 = __builtin_amdgcn_exp2f(-2.885390081777927f * c);
                float th = 2.0f * __builtin_amdgcn_rcpf(1.0f + e2) - 1.0f;
                float hv = go * th;
                if ((lid & 7) == 0) h2sB[cur][jL2] = (__fp16)hv;
            }
        }
        __syncthreads();
    }

    // h2(T-1) is in h2sB[0] (written at iter t=1024, cur=0). FC + sigmoid.
    if (tid < HH) {
        float v = (float)h2sB[0][tid] * w_fc[tid];
        #pragma unroll
        for (int off = 32; off > 0; off >>= 1) v += __shfl_down(v, off);
        if (tid == 0) out[b] = fsig(v + b_fc[0]);
    }
}

// ---------------------------------------------------------------------------
// Fallback (R6 structure) if d_ws is too small for gx.
// ---------------------------------------------------------------------------
__global__ __launch_bounds__(512) void lstm2_fb(
    const float* __restrict__ x,
    const float* __restrict__ w_ih_l0, const float* __restrict__ w_hh_l0,
    const float* __restrict__ b_ih_l0, const float* __restrict__ b_hh_l0,
    const float* __restrict__ w_ih_l1, const float* __restrict__ w_hh_l1,
    const float* __restrict__ b_ih_l1, const float* __restrict__ b_hh_l1,
    const float* __restrict__ w_fc,   const float* __restrict__ b_fc,
    float* __restrict__ out)
{
    const int b    = blockIdx.x;
    const int tid  = threadIdx.x;
    const bool isL1 = tid < 256;
    const int gtid = tid & 255;
    const int q    = gtid & 3;
    const int j    = gtid >> 2;
    const int g    = q * 64 + j;

    __shared__ __attribute__((aligned(32))) __fp16 h1s[2][HH];
    __shared__ __attribute__((aligned(32))) __fp16 h2sB[2][HH];
    if (tid < HH) {
        h1s[0][tid] = (__fp16)0.f; h1s[1][tid] = (__fp16)0.f;
        h2sB[0][tid] = (__fp16)0.f; h2sB[1][tid] = (__fp16)0.f;
    }
    const float kk = (q == 2) ? -2.885390081777927f : -1.4426950408889634f;
    const float aa = (q == 2) ? 2.0f : 1.0f;
    const float bb = (q == 2) ? -1.0f : 0.0f;

    h2 wh[64];
    float bias;
    if (isL1) {
        #pragma unroll
        for (int mm = 0; mm < 4; ++mm) {
            const float4* pih = (const float4*)(w_ih_l0 + (mm*64 + j)*DD + q*8);
            float4 f0 = pih[0], f1 = pih[1];
            wh[mm*12+0] = pk(f0.x,f0.y); wh[mm*12+1] = pk(f0.z,f0.w);
            wh[mm*12+2] = pk(f1.x,f1.y); wh[mm*12+3] = pk(f1.z,f1.w);
            const float4* phh = (const float4*)(w_hh_l0 + (mm*64 + j)*HH + q*16);
            #pragma unroll
            for (int i = 0; i < 4; ++i) {
                float4 f = phh[i];
                wh[mm*12+4+2*i]   = pk(f.x,f.y);
                wh[mm*12+4+2*i+1] = pk(f.z,f.w);
            }
        }
        bias = b_ih_l0[g] + b_hh_l0[g];
    } else {
        #pragma unroll
        for (int mm = 0; mm < 4; ++mm) {
            const float4* pih = (const float4*)(w_ih_l1 + (mm*64 + j)*HH + q*16);
            const float4* phh = (const float4*)(w_hh_l1 + (mm*64 + j)*HH + q*16);
            #pragma unroll
            for (int i = 0; i < 4; ++i) {
                float4 f = pih[i];
                wh[mm*16+2*i]   = pk(f.x,f.y);
                wh[mm*16+2*i+1] = pk(f.z,f.w);
            }
            #pragma unroll
            for (int i = 0; i < 4; ++i) {
                float4 f = phh[i];
                wh[mm*16+8+2*i]   = pk(f.x,f.y);
                wh[mm*16+8+2*i+1] = pk(f.z,f.w);
            }
        }
        bias = b_ih_l1[g] + b_hh_l1[g];
    }

    float c = 0.0f;
    const float* xbase = x + (size_t)b * TT * DD + q * 8;
    h2 xh[4];
    if (isL1) {
        const float4* xp = (const float4*)xbase;
        float4 a0 = xp[0], a1 = xp[1];
        xh[0] = pk(a0.x,a0.y); xh[1] = pk(a0.z,a0.w);
        xh[2] = pk(a1.x,a1.y); xh[3] = pk(a1.z,a1.w);
    }
    __syncthreads();

    for (int t = 0; t <= TT; ++t) {
        const int prev = (t + 1) & 1;
        const int cur  = t & 1;
        if (isL1) {
            if (t < TT) {
                const int tn = (t + 1 < TT) ? (t + 1) : t;
                const float4* xp = (const float4*)(xbase + (size_t)tn * DD);
                float4 n0 = xp[0], n1 = xp[1];
                H16 hq = *(const H16*)&h1s[prev][q*16];
                float P[4];
                #pragma unroll
                for (int mm = 0; mm < 4; ++mm) {
                    float s = 0.0f;
                    #pragma unroll
                    for (int k = 0; k < 4; ++k)
                        s = __builtin_amdgcn_fdot2(wh[mm*12 + k], xh[k], s, false);
                    #pragma unroll
                    for (int k = 0; k < 8; ++k)
                        s = __builtin_amdgcn_fdot2(wh[mm*12 + 4 + k], hq.p[k], s, false);
                    P[mm] = s;
                }
                float t0 = P[0] + fdpp<0xB1>(P[0]);
                float t1 = P[1] + fdpp<0xB1>(P[1]);
                float t2 = P[2] + fdpp<0xB1>(P[2]);
                float t3 = P[3] + fdpp<0xB1>(P[3]);
                float Alo = (q & 1) ? t1 : t0;
                float Ahi = (q & 1) ? t3 : t2;
                float ulo = Alo + fdpp<0x4E>(Alo);
                float uhi = Ahi + fdpp<0x4E>(Ahi);
                float S = ((q & 2) ? uhi : ulo) + bias;
                float e = __builtin_amdgcn_exp2f(kk * S);
                float v = aa * __builtin_amdgcn_rcpf(1.0f + e) + bb;
                float gi = fdpp<0x00>(v);
                float gf = fdpp<0x55>(v);
                float gg = fdpp<0xAA>(v);
                float go = fdpp<0xFF>(v);
                c = gf * c + gi * gg;
                float e2 = __builtin_amdgcn_exp2f(-2.885390081777927f * c);
                float th = 2.0f * __builtin_amdgcn_rcpf(1.0f + e2) - 1.0f;
                float hv = go * th;
                if (q == 0) h1s[cur][j] = (__fp16)hv;
                xh[0] = pk(n0.x,n0.y); xh[1] = pk(n0.z,n0.w);
                xh[2] = pk(n1.x,n1.y); xh[3] = pk(n1.z,n1.w);
            }
        } else {
            if (t > 0) {
                H16 a1 = *(const H16*)&h1s[prev][q*16];
                H16 a2 = *(const H16*)&h2sB[prev][q*16];
                float P[4];
                #pragma unroll
                for (int mm = 0; mm < 4; ++mm) {
                    float s = 0.0f;
                    #pragma unroll
                    for (int k = 0; k < 8; ++k)
                        s = __builtin_amdgcn_fdot2(wh[mm*16 + k], a1.p[k], s, false);
                    #pragma unroll
                    for (int k = 0; k < 8; ++k)
                        s = __builtin_amdgcn_fdot2(wh[mm*16 + 8 + k], a2.p[k], s, false);
                    P[mm] = s;
                }
                float t0 = P[0] + fdpp<0xB1>(P[0]);
                float t1 = P[1] + fdpp<0xB1>(P[1]);
                float t2 = P[2] + fdpp<0xB1>(P[2]);
                float t3 = P[3] + fdpp<0xB1>(P[3]);
                float Alo = (q & 1) ? t1 : t0;
                float Ahi = (q & 1) ? t3 : t2;
                float ulo = Alo + fdpp<0x4E>(Alo);
                float uhi = Ahi + fdpp<0x4E>(Ahi);
                float S = ((q & 2) ? uhi : ulo) + bias;
                float e = __builtin_amdgcn_exp2f(kk * S);
                float v = aa * __builtin_amdgcn_rcpf(1.0f + e) + bb;
                float gi = fdpp<0x00>(v);
                float gf = fdpp<0x55>(v);
                float gg = fdpp<0xAA>(v);
                float go = fdpp<0xFF>(v);
                c = gf * c + gi * gg;
                float e2 = __builtin_amdgcn_exp2f(-2.885390081777927f * c);
                float th = 2.0f * __builtin_amdgcn_rcpf(1.0f + e2) - 1.0f;
                float hv = go * th;
                if (q == 0) h2sB[cur][j] = (__fp16)hv;
            }
        }
        __syncthreads();
    }

    if (tid < HH) {
        float v = (float)h2sB[0][tid] * w_fc[tid];
        #pragma unroll
        for (int off = 32; off > 0; off >>= 1) v += __shfl_down(v, off);
        if (tid == 0) out[b] = fsig(v + b_fc[0]);
    }
}

extern "C" void kernel_launch(void* const* d_in, const int* in_sizes, int n_in,
                              void* d_out, int out_size, void* d_ws, size_t ws_size,
                              hipStream_t stream) {
    const size_t gx_bytes = (size_t)256 * TT * 256 * sizeof(__fp16);  // 134 MB
    if (ws_size >= gx_bytes) {
        __fp16* gx = (__fp16*)d_ws;
        gx_precompute<<<dim3(256 * 16), dim3(256), 0, stream>>>(
            (const float*)d_in[0], (const float*)d_in[1],
            (const float*)d_in[3], (const float*)d_in[4], gx);
        lstm2_pre<<<dim3(256), dim3(768), 0, stream>>>(
            (const float*)d_in[2],
            (const float*)d_in[5], (const float*)d_in[6],
            (const float*)d_in[7], (const float*)d_in[8],
            (const float*)d_in[9], (const float*)d_in[10],
            gx, (float*)d_out);
    } else {
        lstm2_fb<<<dim3(256), dim3(512), 0, stream>>>(
            (const float*)d_in[0],
            (const float*)d_in[1], (const float*)d_in[2],
            (const float*)d_in[3], (const float*)d_in[4],
            (const float*)d_in[5], (const float*)d_in[6],
            (const float*)d_in[7], (const float*)d_in[8],
            (const float*)d_in[9], (const float*)d_in[10],
            (float*)d_out);
    }
}

// Round 9
// 702.179 us; speedup vs baseline: 1.0016x; 1.0016x over previous
//
#include <hip/hip_runtime.h>

#define TT 1024
#define DD 32
#define HH 64

typedef __fp16 h2 __attribute__((ext_vector_type(2)));

__device__ __forceinline__ float fsig(float x) {
    float e = __builtin_amdgcn_exp2f(-1.4426950408889634f * x);
    return __builtin_amdgcn_rcpf(1.0f + e);
}

template<int CTRL>
__device__ __forceinline__ float fdpp(float x) {
    int r = __builtin_amdgcn_mov_dpp(__builtin_bit_cast(int, x), CTRL, 0xf, 0xf, true);
    return __builtin_bit_cast(float, r);
}

// lane^4 swizzle (BitMode: xor=4, and=0x1F)
__device__ __forceinline__ float fswz4(float x) {
    int r = __builtin_amdgcn_ds_swizzle(__builtin_bit_cast(int, x), 0x101F);
    return __builtin_bit_cast(float, r);
}

struct __attribute__((aligned(16))) H8 { h2 p[4]; };   // 8 f16 = 16 B = one bank-group

__device__ __forceinline__ h2 pk(float a, float b) {
    return __builtin_amdgcn_cvt_pkrtz(a, b);
}

// dot2 via inline asm: operands REQUIRE arch VGPRs, so the register allocator
// cannot profitably park weights in AGPRs (which cost v_accvgpr_read per use).
__device__ __forceinline__ void vdot(float& s, h2 w, h2 h) {
    asm("v_dot2_f32_f16 %0, %1, %2, %0" : "+v"(s) : "v"(w), "v"(h));
}

// ---------------------------------------------------------------------------
// Kernel 1: gx[b][t][j*4+q] = x[b][t] . W_ih_l0[q*64+j] + b_ih + b_hh  (f16)
// ---------------------------------------------------------------------------
__global__ __launch_bounds__(256) void gx_precompute(
    const float* __restrict__ x, const float* __restrict__ w_ih_l0,
    const float* __restrict__ b_ih_l0, const float* __restrict__ b_hh_l0,
    __fp16* __restrict__ gx)
{
    const int blk = blockIdx.x;
    const int b   = blk >> 4;
    const int tq  = blk & 15;
    const int tid = threadIdx.x;
    const int q   = tid & 3;
    const int j   = tid >> 2;
    const int g   = q * 64 + j;

    __shared__ __attribute__((aligned(16))) h2 xlds[512];   // 32 t x 32 k (f16)

    h2 wk[16];
    {
        const float4* wp = (const float4*)(w_ih_l0 + g * DD);
        #pragma unroll
        for (int i = 0; i < 8; ++i) {
            float4 f = wp[i];
            wk[2*i]   = pk(f.x, f.y);
            wk[2*i+1] = pk(f.z, f.w);
        }
    }
    const float bias = b_ih_l0[g] + b_hh_l0[g];

    const float* xb = x + (size_t)b * (TT*DD) + tq * 64 * DD;
    __fp16* gxo = gx + ((size_t)b * TT + tq * 64) * 256 + tid;

    #pragma unroll
    for (int sc = 0; sc < 2; ++sc) {
        __syncthreads();
        {
            float4 f = *(const float4*)(xb + sc * 1024 + tid * 4);
            xlds[tid*2]   = pk(f.x, f.y);
            xlds[tid*2+1] = pk(f.z, f.w);
        }
        __syncthreads();
        for (int tl = 0; tl < 32; ++tl) {
            float s0 = 0.f, s1 = 0.f;
            #pragma unroll
            for (int k = 0; k < 8; ++k) s0 = __builtin_amdgcn_fdot2(wk[k],   xlds[tl*16 + k],     s0, false);
            #pragma unroll
            for (int k = 0; k < 8; ++k) s1 = __builtin_amdgcn_fdot2(wk[8+k], xlds[tl*16 + 8 + k], s1, false);
            gxo[(sc*32 + tl) * 256] = (__fp16)(s0 + s1 + bias);
        }
    }
}

// ---------------------------------------------------------------------------
// Kernel 2: recurrence. 768 threads/block, block = batch element.
//  tid<256  : L1. lid=tid; j=lid>>2, q=lid&3. Full K=64 h-dot; x-part via gx.
//  tid>=256 : L2. lid=tid-256; j=lid>>3, gate=lid&3, half=(lid>>2)&1.
//             Split-K halves (h1 / h2); xor-4 swizzle combine.
// h state stored REPLICATED (h[0..63] and copy at +64) so each lane reads its
// 8 16B-chunks starting at rotation r=lid&7 linearly: every ds_read_b128 has
// 8 distinct addresses covering all 32 banks -> no conflicts, no mask VALU.
// Weights stored per-lane in matching rotated chunk order.
// ---------------------------------------------------------------------------
__global__ __launch_bounds__(768) void lstm2_rot(
    const float* __restrict__ w_hh_l0,
    const float* __restrict__ w_ih_l1, const float* __restrict__ w_hh_l1,
    const float* __restrict__ b_ih_l1, const float* __restrict__ b_hh_l1,
    const float* __restrict__ w_fc,   const float* __restrict__ b_fc,
    const __fp16* __restrict__ gx,
    float* __restrict__ out)
{
    const int b    = blockIdx.x;
    const int tid  = threadIdx.x;
    const bool isL1 = tid < 256;
    const int lid  = isL1 ? tid : (tid - 256);
    const int q    = lid & 3;            // gate (both groups)
    const int jL1  = lid >> 2;
    const int half = (lid >> 2) & 1;     // L2 K-half
    const int jL2  = lid >> 3;
    const int r    = lid & 7;            // chunk rotation

    __shared__ __attribute__((aligned(16))) __fp16 h1s[2][128];
    __shared__ __attribute__((aligned(16))) __fp16 h2s[2][128];
    if (tid < 128) {
        h1s[0][tid] = (__fp16)0.f; h1s[1][tid] = (__fp16)0.f;
        h2s[0][tid] = (__fp16)0.f; h2s[1][tid] = (__fp16)0.f;
    }

    const float kk = (q == 2) ? -2.885390081777927f : -1.4426950408889634f;
    const float aa = (q == 2) ? 2.0f : 1.0f;
    const float bb = (q == 2) ? -1.0f : 0.0f;

    // 32 packed-f16 weight dwords per lane, chunk-rotated by r.
    h2 wh[32];
    float bias = 0.f;
    {
        const float* wrow;
        if (isL1) {
            wrow = w_hh_l0 + (q*64 + jL1) * HH;
        } else {
            const int g2 = q*64 + jL2;
            wrow = half ? (w_hh_l1 + g2 * HH) : (w_ih_l1 + g2 * HH);
            bias = b_ih_l1[g2] + b_hh_l1[g2];
        }
        #pragma unroll
        for (int i = 0; i < 8; ++i) {
            const int c = (i + r) & 7;
            float4 f0 = *(const float4*)(wrow + c*8);
            float4 f1 = *(const float4*)(wrow + c*8 + 4);
            wh[4*i+0] = pk(f0.x, f0.y);
            wh[4*i+1] = pk(f0.z, f0.w);
            wh[4*i+2] = pk(f1.x, f1.y);
            wh[4*i+3] = pk(f1.z, f1.w);
        }
    }

    float c = 0.0f;

    const __fp16* gxp = gx + ((size_t)b << 18) + lid;
    float gxv = isL1 ? (float)gxp[0] : 0.f;

    __syncthreads();

    for (int t = 0; t <= TT; ++t) {
        const int prev = (t + 1) & 1;
        const int cur  = t & 1;
        if (isL1) {
            if (t < TT) {
                const int tn = (t + 1 < TT) ? (t + 1) : t;
                float gnext = (float)gxp[(size_t)tn << 8];

                const H8* hc = (const H8*)&h1s[prev][0];
                H8 c0 = hc[r+0], c1 = hc[r+1], c2 = hc[r+2], c3 = hc[r+3];
                float p0 = gxv, p1 = 0.f, p2 = 0.f, p3 = 0.f;
                #pragma unroll
                for (int k = 0; k < 4; ++k) {
                    vdot(p0, wh[k],      c0.p[k]);
                    vdot(p1, wh[4 + k],  c1.p[k]);
                    vdot(p2, wh[8 + k],  c2.p[k]);
                    vdot(p3, wh[12 + k], c3.p[k]);
                }
                H8 c4 = hc[r+4], c5 = hc[r+5], c6 = hc[r+6], c7 = hc[r+7];
                #pragma unroll
                for (int k = 0; k < 4; ++k) {
                    vdot(p0, wh[16 + k], c4.p[k]);
                    vdot(p1, wh[20 + k], c5.p[k]);
                    vdot(p2, wh[24 + k], c6.p[k]);
                    vdot(p3, wh[28 + k], c7.p[k]);
                }
                float S = (p0 + p1) + (p2 + p3);

                float e = __builtin_amdgcn_exp2f(kk * S);
                float v = aa * __builtin_amdgcn_rcpf(1.0f + e) + bb;

                float gi = fdpp<0x00>(v);
                float gf = fdpp<0x55>(v);
                float gg = fdpp<0xAA>(v);
                float go = fdpp<0xFF>(v);
                c = gf * c + gi * gg;
                float e2 = __builtin_amdgcn_exp2f(-2.885390081777927f * c);
                float th = 2.0f * __builtin_amdgcn_rcpf(1.0f + e2) - 1.0f;
                float hv = go * th;
                if (q == 0) {
                    __fp16 hv16 = (__fp16)hv;
                    h1s[cur][jL1]      = hv16;
                    h1s[cur][64 + jL1] = hv16;
                }
                gxv = gnext;
            }
        } else {
            if (t > 0) {
                const H8* hc = half ? (const H8*)&h2s[prev][0]
                                    : (const H8*)&h1s[prev][0];
                H8 c0 = hc[r+0], c1 = hc[r+1], c2 = hc[r+2], c3 = hc[r+3];
                float p0 = 0.f, p1 = 0.f, p2 = 0.f, p3 = 0.f;
                #pragma unroll
                for (int k = 0; k < 4; ++k) {
                    vdot(p0, wh[k],      c0.p[k]);
                    vdot(p1, wh[4 + k],  c1.p[k]);
                    vdot(p2, wh[8 + k],  c2.p[k]);
                    vdot(p3, wh[12 + k], c3.p[k]);
                }
                H8 c4 = hc[r+4], c5 = hc[r+5], c6 = hc[r+6], c7 = hc[r+7];
                #pragma unroll
                for (int k = 0; k < 4; ++k) {
                    vdot(p0, wh[16 + k], c4.p[k]);
                    vdot(p1, wh[20 + k], c5.p[k]);
                    vdot(p2, wh[24 + k], c6.p[k]);
                    vdot(p3, wh[28 + k], c7.p[k]);
                }
                float Sp = (p0 + p1) + (p2 + p3);
                float S = Sp + fswz4(Sp) + bias;

                float e = __builtin_amdgcn_exp2f(kk * S);
                float v = aa * __builtin_amdgcn_rcpf(1.0f + e) + bb;

                float gi = fdpp<0x00>(v);
                float gf = fdpp<0x55>(v);
                float gg = fdpp<0xAA>(v);
                float go = fdpp<0xFF>(v);
                c = gf * c + gi * gg;
                float e2 = __builtin_amdgcn_exp2f(-2.885390081777927f * c);
                float th = 2.0f * __builtin_amdgcn_rcpf(1.0f + e2) - 1.0f;
                float hv = go * th;
                if ((lid & 7) == 0) {
                    __fp16 hv16 = (__fp16)hv;
                    h2s[cur][jL2]      = hv16;
                    h2s[cur][64 + jL2] = hv16;
                }
            }
        }
        __syncthreads();
    }

    // h2(T-1) is in h2s[0] (written at iter t=1024, cur=0). FC + sigmoid.
    if (tid < HH) {
        float v = (float)h2s[0][tid] * w_fc[tid];
        #pragma unroll
        for (int off = 32; off > 0; off >>= 1) v += __shfl_down(v, off);
        if (tid == 0) out[b] = fsig(v + b_fc[0]);
    }
}

extern "C" void kernel_launch(void* const* d_in, const int* in_sizes, int n_in,
                              void* d_out, int out_size, void* d_ws, size_t ws_size,
                              hipStream_t stream) {
    __fp16* gx = (__fp16*)d_ws;   // 134 MB (ws_size verified sufficient in R8)
    gx_precompute<<<dim3(256 * 16), dim3(256), 0, stream>>>(
        (const float*)d_in[0], (const float*)d_in[1],
        (const float*)d_in[3], (const float*)d_in[4], gx);
    lstm2_rot<<<dim3(256), dim3(768), 0, stream>>>(
        (const float*)d_in[2],
        (const float*)d_in[5], (const float*)d_in[6],
        (const float*)d_in[7], (const float*)d_in[8],
        (const float*)d_in[9], (const float*)d_in[10],
        gx, (float*)d_out);
}

// Round 10
// 556.471 us; speedup vs baseline: 1.2639x; 1.2618x over previous
//
#include <hip/hip_runtime.h>

#define TT 1024
#define DD 32
#define HH 64

typedef __fp16 h2v __attribute__((ext_vector_type(2)));
typedef _Float16 f16x8 __attribute__((ext_vector_type(8)));
typedef float f32x4 __attribute__((ext_vector_type(4)));

struct __attribute__((aligned(16))) H4 { h2v p[4]; };
struct __attribute__((aligned(8)))  GX2 { h2v a, b; };

__device__ __forceinline__ h2v pk(float a, float b) {
    return __builtin_amdgcn_cvt_pkrtz(a, b);
}
__device__ __forceinline__ float fsig(float x) {
    float e = __builtin_amdgcn_exp2f(-1.4426950408889634f * x);
    return __builtin_amdgcn_rcpf(1.0f + e);
}
__device__ __forceinline__ float ftanh(float x) {
    float e = __builtin_amdgcn_exp2f(2.885390081777927f * x);
    return 1.0f - 2.0f * __builtin_amdgcn_rcpf(1.0f + e);
}
// select element (lane&3) of a C-fragment: 3 cndmasks
__device__ __forceinline__ float pick4(f32x4 c, bool s0, bool s1) {
    float lo = s0 ? c[1] : c[0];
    float hi = s0 ? c[3] : c[2];
    return s1 ? hi : lo;
}
// A-fragment: 8 consecutive fp32 weights -> packed f16 (lane holds A[m=lane&15][k=quad*8+i])
__device__ __forceinline__ f16x8 load_afrag(const float* p) {
    float4 f0 = *(const float4*)p;
    float4 f1 = *(const float4*)(p + 4);
    H4 t;
    t.p[0] = pk(f0.x, f0.y); t.p[1] = pk(f0.z, f0.w);
    t.p[2] = pk(f1.x, f1.y); t.p[3] = pk(f1.z, f1.w);
    return __builtin_bit_cast(f16x8, t);
}

#define MFMA16(A, B, C) __builtin_amdgcn_mfma_f32_16x16x32_f16(A, B, C, 0, 0, 0)

// ---------------------------------------------------------------------------
// Kernel 1 (unchanged from R8): gx[b][t][j*4+q] = x[b][t].W_ih_l0[q*64+j] + biases (f16)
// ---------------------------------------------------------------------------
__global__ __launch_bounds__(256) void gx_precompute(
    const float* __restrict__ x, const float* __restrict__ w_ih_l0,
    const float* __restrict__ b_ih_l0, const float* __restrict__ b_hh_l0,
    __fp16* __restrict__ gx)
{
    const int blk = blockIdx.x;
    const int b   = blk >> 4;
    const int tq  = blk & 15;
    const int tid = threadIdx.x;
    const int q   = tid & 3;
    const int j   = tid >> 2;
    const int g   = q * 64 + j;

    __shared__ __attribute__((aligned(16))) h2v xlds[512];

    h2v wk[16];
    {
        const float4* wp = (const float4*)(w_ih_l0 + g * DD);
        #pragma unroll
        for (int i = 0; i < 8; ++i) {
            float4 f = wp[i];
            wk[2*i]   = pk(f.x, f.y);
            wk[2*i+1] = pk(f.z, f.w);
        }
    }
    const float bias = b_ih_l0[g] + b_hh_l0[g];

    const float* xb = x + (size_t)b * (TT*DD) + tq * 64 * DD;
    __fp16* gxo = gx + ((size_t)b * TT + tq * 64) * 256 + tid;

    #pragma unroll
    for (int sc = 0; sc < 2; ++sc) {
        __syncthreads();
        {
            float4 f = *(const float4*)(xb + sc * 1024 + tid * 4);
            xlds[tid*2]   = pk(f.x, f.y);
            xlds[tid*2+1] = pk(f.z, f.w);
        }
        __syncthreads();
        for (int tl = 0; tl < 32; ++tl) {
            float s0 = 0.f, s1 = 0.f;
            #pragma unroll
            for (int k = 0; k < 8; ++k) s0 = __builtin_amdgcn_fdot2(wk[k],   xlds[tl*16 + k],     s0, false);
            #pragma unroll
            for (int k = 0; k < 8; ++k) s1 = __builtin_amdgcn_fdot2(wk[8+k], xlds[tl*16 + 8 + k], s1, false);
            gxo[(sc*32 + tl) * 256] = (__fp16)(s0 + s1 + bias);
        }
    }
}

// ---------------------------------------------------------------------------
// Kernel 2: recurrence via MFMA. 512 thr = 8 waves; block = batch element.
//  waves 0-3 : L1, wave w owns j in [16w,16w+16). 4 C-chains (gates) x 2 K-halves
//              = 8 MFMA/step. x-part comes from gx.
//  waves 4-7 : L2 (one step behind). 16 MFMA/step (W_ih@h1 + W_hh@h2 chained).
// B operand = h replicated across all 16 cols -> ds_read_b128 broadcast, and C
// cols all equal -> gates live in every lane's C regs (no LDS round-trip).
// Lane (quad=lane>>4, r=lane&3) activates j_act = 16w + quad*4 + r via cndmask
// row-select; lanes with (lane&12)==0 write h to LDS.
// ---------------------------------------------------------------------------
__global__ __launch_bounds__(512) void lstm2_mfma(
    const float* __restrict__ w_hh_l0,
    const float* __restrict__ w_ih_l1, const float* __restrict__ w_hh_l1,
    const float* __restrict__ b_ih_l1, const float* __restrict__ b_hh_l1,
    const float* __restrict__ w_fc,   const float* __restrict__ b_fc,
    const __fp16* __restrict__ gx,
    float* __restrict__ out)
{
    const int b    = blockIdx.x;
    const int tid  = threadIdx.x;
    const int wave = tid >> 6;
    const int lane = tid & 63;
    const bool isL1 = wave < 4;
    const int w    = isL1 ? wave : (wave - 4);
    const int colg = lane & 15;          // A-row within tile
    const int quad = lane >> 4;
    const int j_act = 16*w + quad*4 + (lane & 3);

    __shared__ __attribute__((aligned(16))) __fp16 h1s[2][HH];
    __shared__ __attribute__((aligned(16))) __fp16 h2s[2][HH];
    if (tid < HH) {
        h1s[0][tid] = (__fp16)0.f; h1s[1][tid] = (__fp16)0.f;
        h2s[0][tid] = (__fp16)0.f; h2s[1][tid] = (__fp16)0.f;
    }

    // A fragments (weights). L1: Ahh = W_hh_l0. L2: Aih = W_ih_l1, Ahh = W_hh_l1.
    f16x8 Aih[8], Ahh[8];
    float bias0 = 0.f, bias1 = 0.f, bias2 = 0.f, bias3 = 0.f;
    if (isL1) {
        #pragma unroll
        for (int q = 0; q < 4; ++q)
            #pragma unroll
            for (int kh = 0; kh < 2; ++kh)
                Ahh[q*2+kh] = load_afrag(w_hh_l0 + (size_t)(q*64 + 16*w + colg)*HH + kh*32 + quad*8);
    } else {
        #pragma unroll
        for (int q = 0; q < 4; ++q)
            #pragma unroll
            for (int kh = 0; kh < 2; ++kh) {
                Aih[q*2+kh] = load_afrag(w_ih_l1 + (size_t)(q*64 + 16*w + colg)*HH + kh*32 + quad*8);
                Ahh[q*2+kh] = load_afrag(w_hh_l1 + (size_t)(q*64 + 16*w + colg)*HH + kh*32 + quad*8);
            }
        bias0 = b_ih_l1[0*64 + j_act] + b_hh_l1[0*64 + j_act];
        bias1 = b_ih_l1[1*64 + j_act] + b_hh_l1[1*64 + j_act];
        bias2 = b_ih_l1[2*64 + j_act] + b_hh_l1[2*64 + j_act];
        bias3 = b_ih_l1[3*64 + j_act] + b_hh_l1[3*64 + j_act];
    }

    // gx stream (L1): 4 f16 per step = gates i,f,g,o of j_act
    const __fp16* gxp = gx + ((size_t)b << 18) + j_act * 4;
    GX2 gq = {};
    if (isL1) gq = *(const GX2*)gxp;

    const bool s0 = (lane & 1) != 0;
    const bool s1 = (lane & 2) != 0;
    float c = 0.0f;

    __syncthreads();

    for (int t = 0; t <= TT; ++t) {
        const int prev = (t + 1) & 1;
        const int cur  = t & 1;
        if (isL1) {
            if (t < TT) {
                const int tn = (t + 1 < TT) ? (t + 1) : t;
                GX2 gn = *(const GX2*)(gxp + ((size_t)tn << 8));

                const __fp16* hp = &h1s[prev][0];
                f16x8 Blo = *(const f16x8*)(hp + quad*8);
                f16x8 Bhi = *(const f16x8*)(hp + 32 + quad*8);

                f32x4 Z = {0.f, 0.f, 0.f, 0.f};
                f32x4 C0 = Z, C1 = Z, C2 = Z, C3 = Z;
                C0 = MFMA16(Ahh[0], Blo, C0); C0 = MFMA16(Ahh[1], Bhi, C0);
                C1 = MFMA16(Ahh[2], Blo, C1); C1 = MFMA16(Ahh[3], Bhi, C1);
                C2 = MFMA16(Ahh[4], Blo, C2); C2 = MFMA16(Ahh[5], Bhi, C2);
                C3 = MFMA16(Ahh[6], Blo, C3); C3 = MFMA16(Ahh[7], Bhi, C3);

                float Si = pick4(C0, s0, s1) + (float)gq.a[0];
                float Sf = pick4(C1, s0, s1) + (float)gq.a[1];
                float Sg = pick4(C2, s0, s1) + (float)gq.b[0];
                float So = pick4(C3, s0, s1) + (float)gq.b[1];

                float ii = fsig(Si), ff = fsig(Sf), oo = fsig(So);
                float gg = ftanh(Sg);
                c = ff * c + ii * gg;
                float hv = oo * ftanh(c);
                if ((lane & 12) == 0) h1s[cur][j_act] = (__fp16)hv;
                gq = gn;
            }
        } else {
            if (t > 0) {
                const __fp16* hp1 = &h1s[prev][0];
                const __fp16* hp2 = &h2s[prev][0];
                f16x8 B1lo = *(const f16x8*)(hp1 + quad*8);
                f16x8 B1hi = *(const f16x8*)(hp1 + 32 + quad*8);
                f16x8 B2lo = *(const f16x8*)(hp2 + quad*8);
                f16x8 B2hi = *(const f16x8*)(hp2 + 32 + quad*8);

                f32x4 Z = {0.f, 0.f, 0.f, 0.f};
                f32x4 C0 = Z, C1 = Z, C2 = Z, C3 = Z;
                C0 = MFMA16(Aih[0], B1lo, C0); C0 = MFMA16(Aih[1], B1hi, C0);
                C0 = MFMA16(Ahh[0], B2lo, C0); C0 = MFMA16(Ahh[1], B2hi, C0);
                C1 = MFMA16(Aih[2], B1lo, C1); C1 = MFMA16(Aih[3], B1hi, C1);
                C1 = MFMA16(Ahh[2], B2lo, C1); C1 = MFMA16(Ahh[3], B2hi, C1);
                C2 = MFMA16(Aih[4], B1lo, C2); C2 = MFMA16(Aih[5], B1hi, C2);
                C2 = MFMA16(Ahh[4], B2lo, C2); C2 = MFMA16(Ahh[5], B2hi, C2);
                C3 = MFMA16(Aih[6], B1lo, C3); C3 = MFMA16(Aih[7], B1hi, C3);
                C3 = MFMA16(Ahh[6], B2lo, C3); C3 = MFMA16(Ahh[7], B2hi, C3);

                float Si = pick4(C0, s0, s1) + bias0;
                float Sf = pick4(C1, s0, s1) + bias1;
                float Sg = pick4(C2, s0, s1) + bias2;
                float So = pick4(C3, s0, s1) + bias3;

                float ii = fsig(Si), ff = fsig(Sf), oo = fsig(So);
                float gg = ftanh(Sg);
                c = ff * c + ii * gg;
                float hv = oo * ftanh(c);
                if ((lane & 12) == 0) h2s[cur][j_act] = (__fp16)hv;
            }
        }
        __syncthreads();
    }

    // h2(T-1) is in h2s[0] (last write at t=1024, cur=0). FC + sigmoid.
    if (tid < HH) {
        float v = (float)h2s[0][tid] * w_fc[tid];
        #pragma unroll
        for (int off = 32; off > 0; off >>= 1) v += __shfl_down(v, off);
        if (tid == 0) out[b] = fsig(v + b_fc[0]);
    }
}

extern "C" void kernel_launch(void* const* d_in, const int* in_sizes, int n_in,
                              void* d_out, int out_size, void* d_ws, size_t ws_size,
                              hipStream_t stream) {
    __fp16* gx = (__fp16*)d_ws;   // 134 MB, ws_size verified sufficient in R8/R9
    gx_precompute<<<dim3(256 * 16), dim3(256), 0, stream>>>(
        (const float*)d_in[0], (const float*)d_in[1],
        (const float*)d_in[3], (const float*)d_in[4], gx);
    lstm2_mfma<<<dim3(256), dim3(512), 0, stream>>>(
        (const float*)d_in[2],
        (const float*)d_in[5], (const float*)d_in[6],
        (const float*)d_in[7], (const float*)d_in[8],
        (const float*)d_in[9], (const float*)d_in[10],
        gx, (float*)d_out);
}